// Round 10
// baseline (305.633 us; speedup 1.0000x reference)
//
#include <hip/hip_runtime.h>
#include <cstdint>
#include <cstddef>

// ---------------------------------------------------------------------------
// GCN 2-layer + 2 heads. N=100000 (<2^17), E=1.6M.
//   pass1/pass2: CSR (slack-capacity segmented buckets, LDS counting sort)
//   cast:   xh = bf16(dinv ⊙ x)   (prescaled -> pull1 is a plain row-sum)
//   pull1:  agg = dinv ⊙ (row-sum of xh over nbrs+self)
//   gemm1:  h1 = relu(agg@W1 + b1)            (reg-blocked 8x4/thread)
//   gemm2:  g2h = bf16(dinv ⊙ (h1@W2))        (reg-blocked 4x4/thread)
//   pull2:  plain bf16 row-sum + relu + both heads fused
// R4: gathers stay VGPR-lean. R9: pulls are VALU-bound, not BW-bound ->
// this round: prescale (no per-edge weights), 32-bit saddr addressing,
// float2 packed adds (v_pk_add_f32), A/B accumulator split.
// ---------------------------------------------------------------------------

#define MAXC 512   // max coarse buckets (N <= 131072)
#define CAP  6144  // slots per bucket; mean 4093, sigma 64 -> no overflow
#define SEG  3456  // max edges per pass1 block (LDS-staged)
#define GPAD 16    // gcur stride in ints (one counter per 64B line)

__device__ __forceinline__ float blo(unsigned int u) {
  return __uint_as_float(u << 16);
}
__device__ __forceinline__ float bhi(unsigned int u) {
  return __uint_as_float(u & 0xffff0000u);
}
__device__ __forceinline__ unsigned short f2b(float f) {  // RNE pack
  unsigned int u = __float_as_uint(f);
  unsigned int r = u + 0x7fffu + ((u >> 16) & 1u);
  return (unsigned short)(r >> 16);
}

// --- cast: xh[row] = bf16(dinv[row] * x[row])  (after pass2) ---
__global__ __launch_bounds__(256) void k_cast(const float* __restrict__ x,
                                              const float* __restrict__ dinv,
                                              unsigned int* __restrict__ xh,
                                              int n16) {  // n16 = N*16
  int i = blockIdx.x * 256 + threadIdx.x;
  if (i >= n16) return;
  float di = dinv[i >> 4];
  float4 v = reinterpret_cast<const float4*>(x)[i];
  uint2 o;
  o.x = (unsigned int)f2b(v.x * di) | ((unsigned int)f2b(v.y * di) << 16);
  o.y = (unsigned int)f2b(v.z * di) | ((unsigned int)f2b(v.w * di) << 16);
  reinterpret_cast<uint2*>(xh)[i] = o;
}

// --- bucket cursors: segmented regions of CAP slots, line-padded ---
__global__ void k_binit(int* __restrict__ gcur, int nc) {
  int b = blockIdx.x * 256 + threadIdx.x;
  if (b < nc) gcur[b * GPAD] = b * CAP;
}

// --- pass1: block-local counting sort by bucket, coalesced write-out ---
__global__ __launch_bounds__(256) void k_pass1(const int* __restrict__ src,
                                               const int* __restrict__ dst,
                                               int* __restrict__ gcur,
                                               int* __restrict__ P,
                                               int E, int nc, int seg) {
  __shared__ int hist[MAXC];
  __shared__ int lofs[MAXC];
  __shared__ int base[MAXC];
  __shared__ int sbuf[SEG];
  __shared__ unsigned short dbuf[SEG];
  __shared__ int ssc[256];
  int tid = threadIdx.x;
  int start = blockIdx.x * seg;
  int end = min(E, start + seg);
  int cnt = end - start;
  if (cnt <= 0) return;
  for (int i = tid; i < MAXC; i += 256) hist[i] = 0;
  __syncthreads();
  for (int i = start + tid; i < end; i += 256)
    atomicAdd(&hist[dst[i] >> 8], 1);
  __syncthreads();
  int p0 = hist[2 * tid], p1 = hist[2 * tid + 1];
  int ps = p0 + p1;
  ssc[tid] = ps;
  __syncthreads();
  for (int off = 1; off < 256; off <<= 1) {
    int t = (tid >= off) ? ssc[tid - off] : 0;
    __syncthreads();
    ssc[tid] += t;
    __syncthreads();
  }
  int pe = ssc[tid] - ps;
  lofs[2 * tid] = pe;
  lofs[2 * tid + 1] = pe + p0;
  __syncthreads();
  for (int b = tid; b < nc; b += 256) {
    int h = hist[b];
    base[b] = (h ? atomicAdd(&gcur[b * GPAD], h) : 0) - lofs[b];
  }
  __syncthreads();
  for (int i = tid; i < MAXC; i += 256) hist[i] = lofs[i];
  __syncthreads();
  for (int i = start + tid; i < end; i += 256) {
    int d = dst[i];
    int b = d >> 8;
    int r = atomicAdd(&hist[b], 1);
    sbuf[r] = src[i] | ((d & 255) << 17);
    dbuf[r] = (unsigned short)b;
  }
  __syncthreads();
  for (int j = tid; j < cnt; j += 256) {
    P[base[dbuf[j]] + j] = sbuf[j];
  }
}

// --- per-bucket: LDS count+scan -> rs/c/dinv, then place col ---
__global__ __launch_bounds__(256) void k_pass2(const int* __restrict__ P,
                                               const int* __restrict__ gcur,
                                               int* __restrict__ rs,
                                               int* __restrict__ c,
                                               float* __restrict__ dinv,
                                               int* __restrict__ col, int N) {
  __shared__ int sh[256];
  __shared__ int lcur[256];
  int tid = threadIdx.x;
  int node0 = blockIdx.x << 8;
  int begin = blockIdx.x * CAP;
  int end = gcur[blockIdx.x * GPAD];
  sh[tid] = 0;
  __syncthreads();
  for (int i = begin + tid; i < end; i += 256)
    atomicAdd(&sh[P[i] >> 17], 1);
  __syncthreads();
  int s = sh[tid];
  for (int off = 1; off < 256; off <<= 1) {
    int t = (tid >= off) ? sh[tid - off] : 0;
    __syncthreads();
    sh[tid] += t;
    __syncthreads();
  }
  int excl = sh[tid] - s;
  int node = node0 + tid;
  if (node < N) {
    rs[node] = begin + excl;
    c[node] = s;
    dinv[node] = rsqrtf((float)(s + 1));
  }
  lcur[tid] = begin + excl;
  __syncthreads();
  for (int i = begin + tid; i < end; i += 256) {
    int p = P[i];
    int pos = atomicAdd(&lcur[p >> 17], 1);
    col[pos] = p & 0x1FFFF;
  }
}

// --- pull1: plain bf16 row-sum of prescaled xh (nbrs + self), x di ---
__global__ __launch_bounds__(256) void k_pull1(const unsigned int* __restrict__ xh,
                                               const int* __restrict__ rs,
                                               const int* __restrict__ cnt,
                                               const int* __restrict__ col,
                                               const float* __restrict__ dinv,
                                               float* __restrict__ agg, int n) {
  int node = (blockIdx.x * 256 + threadIdx.x) >> 6;
  int lane = threadIdx.x & 63;
  if (node >= n) return;
  unsigned int q = lane & 15;
  int grp = lane >> 4;
  float di = dinv[node];
  int start = rs[node], m = cnt[node];
  const uint2* xr = reinterpret_cast<const uint2*>(xh);
  float2 a01 = {0.f, 0.f}, a23 = {0.f, 0.f};
  float2 b01 = {0.f, 0.f}, b23 = {0.f, 0.f};
  for (int base0 = 0; base0 < m; base0 += 64) {
    int lim = min(64, m - base0);
    int idx = (lane < lim) ? col[start + base0 + lane] : 0;
    int nt = lim >> 2;
    int t = 0;
    for (; t + 4 <= nt; t += 4) {
      int e0 = t * 4 + grp, e1 = e0 + 4, e2 = e0 + 8, e3 = e0 + 12;
      unsigned int s0 = (unsigned int)__shfl(idx, e0);
      unsigned int s1 = (unsigned int)__shfl(idx, e1);
      unsigned int s2 = (unsigned int)__shfl(idx, e2);
      unsigned int s3 = (unsigned int)__shfl(idx, e3);
      uint2 v0 = xr[(s0 << 4) + q];
      uint2 v1 = xr[(s1 << 4) + q];
      uint2 v2 = xr[(s2 << 4) + q];
      uint2 v3 = xr[(s3 << 4) + q];
      a01 += make_float2(blo(v0.x), bhi(v0.x));
      a23 += make_float2(blo(v0.y), bhi(v0.y));
      b01 += make_float2(blo(v1.x), bhi(v1.x));
      b23 += make_float2(blo(v1.y), bhi(v1.y));
      a01 += make_float2(blo(v2.x), bhi(v2.x));
      a23 += make_float2(blo(v2.y), bhi(v2.y));
      b01 += make_float2(blo(v3.x), bhi(v3.x));
      b23 += make_float2(blo(v3.y), bhi(v3.y));
    }
    for (; t < nt; ++t) {
      int e0 = t * 4 + grp;
      unsigned int s0 = (unsigned int)__shfl(idx, e0);
      uint2 v0 = xr[(s0 << 4) + q];
      a01 += make_float2(blo(v0.x), bhi(v0.x));
      a23 += make_float2(blo(v0.y), bhi(v0.y));
    }
    for (int j = nt * 4; j < lim; ++j) {
      unsigned int s0 = (unsigned int)__shfl(idx, j);
      if (grp == (j & 3)) {
        uint2 v0 = xr[(s0 << 4) + q];
        a01 += make_float2(blo(v0.x), bhi(v0.x));
        a23 += make_float2(blo(v0.y), bhi(v0.y));
      }
    }
  }
  float4 acc = {a01.x + b01.x, a01.y + b01.y, a23.x + b23.x, a23.y + b23.y};
  acc.x += __shfl_xor(acc.x, 16); acc.y += __shfl_xor(acc.y, 16);
  acc.z += __shfl_xor(acc.z, 16); acc.w += __shfl_xor(acc.w, 16);
  acc.x += __shfl_xor(acc.x, 32); acc.y += __shfl_xor(acc.y, 32);
  acc.z += __shfl_xor(acc.z, 32); acc.w += __shfl_xor(acc.w, 32);
  {  // self-loop term: xh[node] is already dinv_node * x_node
    uint2 sv = xr[((unsigned int)node << 4) + q];
    acc.x += blo(sv.x); acc.y += bhi(sv.x);
    acc.z += blo(sv.y); acc.w += bhi(sv.y);
  }
  if (lane < 16) {
    float4 o = {acc.x * di, acc.y * di, acc.z * di, acc.w * di};
    *reinterpret_cast<float4*>(agg + (size_t)node * 64 + q * 4) = o;
  }
}

// --- GEMM1: h1 = relu(agg[N,64]@W1[64,128]+b1); 64-row tile, 8x4/thread ---
__global__ __launch_bounds__(256) void k_gemm1(const float* __restrict__ A,
                                               const float* __restrict__ W,
                                               const float* __restrict__ b,
                                               float* __restrict__ h, int n) {
  __shared__ float4 w4[64 * 32];  // 32KB [k][c4]
  __shared__ float xs[64 * 64];   // 16KB [row][k]
  __shared__ float4 bb[32];
  int tid = threadIdx.x;
  {
    const float4* Wv = reinterpret_cast<const float4*>(W);
    for (int i = tid; i < 64 * 32; i += 256) w4[i] = Wv[i];
    if (tid < 32) bb[tid] = reinterpret_cast<const float4*>(b)[tid];
  }
  int tcol = tid & 31;
  int trowg = tid >> 5;
  int ntiles = (n + 63) >> 6;
  for (int tile = blockIdx.x; tile < ntiles; tile += gridDim.x) {
    int row0 = tile << 6;
    __syncthreads();
#pragma unroll
    for (int j = 0; j < 4; ++j) {
      int idx = tid + 256 * j;
      int r = idx >> 4, c4 = idx & 15;
      int row = row0 + r;
      float4 v = (row < n)
          ? reinterpret_cast<const float4*>(A + (size_t)row * 64)[c4]
          : make_float4(0.f, 0.f, 0.f, 0.f);
      *reinterpret_cast<float4*>(xs + r * 64 + c4 * 4) = v;
    }
    __syncthreads();
    float4 acc[8];
#pragma unroll
    for (int i = 0; i < 8; ++i) acc[i] = make_float4(0.f, 0.f, 0.f, 0.f);
#pragma unroll 4
    for (int kk = 0; kk < 16; ++kk) {
      float4 wa = w4[(kk * 4 + 0) * 32 + tcol];
      float4 wb = w4[(kk * 4 + 1) * 32 + tcol];
      float4 wc = w4[(kk * 4 + 2) * 32 + tcol];
      float4 wd = w4[(kk * 4 + 3) * 32 + tcol];
#pragma unroll
      for (int i = 0; i < 8; ++i) {
        float4 xv = *reinterpret_cast<const float4*>(
            xs + (trowg * 8 + i) * 64 + kk * 4);
        acc[i].x = fmaf(xv.x, wa.x, acc[i].x); acc[i].y = fmaf(xv.x, wa.y, acc[i].y);
        acc[i].z = fmaf(xv.x, wa.z, acc[i].z); acc[i].w = fmaf(xv.x, wa.w, acc[i].w);
        acc[i].x = fmaf(xv.y, wb.x, acc[i].x); acc[i].y = fmaf(xv.y, wb.y, acc[i].y);
        acc[i].z = fmaf(xv.y, wb.z, acc[i].z); acc[i].w = fmaf(xv.y, wb.w, acc[i].w);
        acc[i].x = fmaf(xv.z, wc.x, acc[i].x); acc[i].y = fmaf(xv.z, wc.y, acc[i].y);
        acc[i].z = fmaf(xv.z, wc.z, acc[i].z); acc[i].w = fmaf(xv.z, wc.w, acc[i].w);
        acc[i].x = fmaf(xv.w, wd.x, acc[i].x); acc[i].y = fmaf(xv.w, wd.y, acc[i].y);
        acc[i].z = fmaf(xv.w, wd.z, acc[i].z); acc[i].w = fmaf(xv.w, wd.w, acc[i].w);
      }
    }
    float4 bv = bb[tcol];
#pragma unroll
    for (int i = 0; i < 8; ++i) {
      int row = row0 + trowg * 8 + i;
      if (row < n) {
        float4 o = {fmaxf(acc[i].x + bv.x, 0.f), fmaxf(acc[i].y + bv.y, 0.f),
                    fmaxf(acc[i].z + bv.z, 0.f), fmaxf(acc[i].w + bv.w, 0.f)};
        reinterpret_cast<float4*>(h + (size_t)row * 128)[tcol] = o;
      }
    }
  }
}

// --- GEMM2: g2h = bf16(dinv ⊙ (h1[N,128]@W2[128,64])); 64-row, 4x4/thread ---
#define XS2 132  // padded row stride (floats) to avoid 4-way bank conflicts
__global__ __launch_bounds__(256) void k_gemm2(const float* __restrict__ h1,
                                               const float* __restrict__ W,
                                               const float* __restrict__ dinv,
                                               unsigned int* __restrict__ g2h,
                                               int n) {
  __shared__ float4 w4[128 * 16];   // 32KB [k][c4]
  __shared__ float xs[64 * XS2];    // ~33KB padded
  int tid = threadIdx.x;
  {
    const float4* Wv = reinterpret_cast<const float4*>(W);
    for (int i = tid; i < 128 * 16; i += 256) w4[i] = Wv[i];
  }
  int tcol = tid & 15;
  int trowg = tid >> 4;
  int ntiles = (n + 63) >> 6;
  for (int tile = blockIdx.x; tile < ntiles; tile += gridDim.x) {
    int row0 = tile << 6;
    __syncthreads();
#pragma unroll
    for (int j = 0; j < 8; ++j) {
      int idx = tid + 256 * j;
      int r = idx >> 5, c4 = idx & 31;
      int row = row0 + r;
      float4 v = (row < n)
          ? reinterpret_cast<const float4*>(h1 + (size_t)row * 128)[c4]
          : make_float4(0.f, 0.f, 0.f, 0.f);
      *reinterpret_cast<float4*>(xs + r * XS2 + c4 * 4) = v;
    }
    __syncthreads();
    float4 acc[4];
#pragma unroll
    for (int i = 0; i < 4; ++i) acc[i] = make_float4(0.f, 0.f, 0.f, 0.f);
#pragma unroll 4
    for (int kk = 0; kk < 32; ++kk) {
      float4 wa = w4[(kk * 4 + 0) * 16 + tcol];
      float4 wb = w4[(kk * 4 + 1) * 16 + tcol];
      float4 wc = w4[(kk * 4 + 2) * 16 + tcol];
      float4 wd = w4[(kk * 4 + 3) * 16 + tcol];
#pragma unroll
      for (int i = 0; i < 4; ++i) {
        float4 xv = *reinterpret_cast<const float4*>(
            xs + (trowg * 4 + i) * XS2 + kk * 4);
        acc[i].x = fmaf(xv.x, wa.x, acc[i].x); acc[i].y = fmaf(xv.x, wa.y, acc[i].y);
        acc[i].z = fmaf(xv.x, wa.z, acc[i].z); acc[i].w = fmaf(xv.x, wa.w, acc[i].w);
        acc[i].x = fmaf(xv.y, wb.x, acc[i].x); acc[i].y = fmaf(xv.y, wb.y, acc[i].y);
        acc[i].z = fmaf(xv.y, wb.z, acc[i].z); acc[i].w = fmaf(xv.y, wb.w, acc[i].w);
        acc[i].x = fmaf(xv.z, wc.x, acc[i].x); acc[i].y = fmaf(xv.z, wc.y, acc[i].y);
        acc[i].z = fmaf(xv.z, wc.z, acc[i].z); acc[i].w = fmaf(xv.z, wc.w, acc[i].w);
        acc[i].x = fmaf(xv.w, wd.x, acc[i].x); acc[i].y = fmaf(xv.w, wd.y, acc[i].y);
        acc[i].z = fmaf(xv.w, wd.z, acc[i].z); acc[i].w = fmaf(xv.w, wd.w, acc[i].w);
      }
    }
#pragma unroll
    for (int i = 0; i < 4; ++i) {
      int row = row0 + trowg * 4 + i;
      if (row < n) {
        float di = dinv[row];
        uint2 o;
        o.x = (unsigned int)f2b(acc[i].x * di) |
              ((unsigned int)f2b(acc[i].y * di) << 16);
        o.y = (unsigned int)f2b(acc[i].z * di) |
              ((unsigned int)f2b(acc[i].w * di) << 16);
        reinterpret_cast<uint2*>(g2h)[(size_t)row * 16 + tcol] = o;
      }
    }
  }
}

// --- pull2: plain bf16 row-sum + relu + both heads fused ---
__global__ __launch_bounds__(256) void k_pull2(const unsigned int* __restrict__ g2h,
                                               const int* __restrict__ rs,
                                               const int* __restrict__ cnt,
                                               const int* __restrict__ col,
                                               const float* __restrict__ dinv,
                                               const float* __restrict__ b,
                                               const float* __restrict__ Wd,
                                               const float* __restrict__ Wp,
                                               const float* __restrict__ bd,
                                               const float* __restrict__ bp,
                                               float* __restrict__ out, int n) {
  int node = (blockIdx.x * 256 + threadIdx.x) >> 6;
  int lane = threadIdx.x & 63;
  if (node >= n) return;
  unsigned int q = lane & 15;
  int grp = lane >> 4;
  int start = rs[node], m = cnt[node];
  const uint2* gr = reinterpret_cast<const uint2*>(g2h);
  float2 a01 = {0.f, 0.f}, a23 = {0.f, 0.f};
  float2 b01 = {0.f, 0.f}, b23 = {0.f, 0.f};
  for (int base0 = 0; base0 < m; base0 += 64) {
    int lim = min(64, m - base0);
    int idx = (lane < lim) ? col[start + base0 + lane] : 0;
    int nt = lim >> 2;
    int t = 0;
    for (; t + 4 <= nt; t += 4) {
      int e0 = t * 4 + grp, e1 = e0 + 4, e2 = e0 + 8, e3 = e0 + 12;
      unsigned int s0 = (unsigned int)__shfl(idx, e0);
      unsigned int s1 = (unsigned int)__shfl(idx, e1);
      unsigned int s2 = (unsigned int)__shfl(idx, e2);
      unsigned int s3 = (unsigned int)__shfl(idx, e3);
      uint2 v0 = gr[(s0 << 4) + q];
      uint2 v1 = gr[(s1 << 4) + q];
      uint2 v2 = gr[(s2 << 4) + q];
      uint2 v3 = gr[(s3 << 4) + q];
      a01 += make_float2(blo(v0.x), bhi(v0.x));
      a23 += make_float2(blo(v0.y), bhi(v0.y));
      b01 += make_float2(blo(v1.x), bhi(v1.x));
      b23 += make_float2(blo(v1.y), bhi(v1.y));
      a01 += make_float2(blo(v2.x), bhi(v2.x));
      a23 += make_float2(blo(v2.y), bhi(v2.y));
      b01 += make_float2(blo(v3.x), bhi(v3.x));
      b23 += make_float2(blo(v3.y), bhi(v3.y));
    }
    for (; t < nt; ++t) {
      int e0 = t * 4 + grp;
      unsigned int s0 = (unsigned int)__shfl(idx, e0);
      uint2 v0 = gr[(s0 << 4) + q];
      a01 += make_float2(blo(v0.x), bhi(v0.x));
      a23 += make_float2(blo(v0.y), bhi(v0.y));
    }
    for (int j = nt * 4; j < lim; ++j) {
      unsigned int s0 = (unsigned int)__shfl(idx, j);
      if (grp == (j & 3)) {
        uint2 v0 = gr[(s0 << 4) + q];
        a01 += make_float2(blo(v0.x), bhi(v0.x));
        a23 += make_float2(blo(v0.y), bhi(v0.y));
      }
    }
  }
  float4 acc = {a01.x + b01.x, a01.y + b01.y, a23.x + b23.x, a23.y + b23.y};
  acc.x += __shfl_xor(acc.x, 16); acc.y += __shfl_xor(acc.y, 16);
  acc.z += __shfl_xor(acc.z, 16); acc.w += __shfl_xor(acc.w, 16);
  acc.x += __shfl_xor(acc.x, 32); acc.y += __shfl_xor(acc.y, 32);
  acc.z += __shfl_xor(acc.z, 32); acc.w += __shfl_xor(acc.w, 32);
  {
    uint2 sv = gr[((unsigned int)node << 4) + q];
    acc.x += blo(sv.x); acc.y += bhi(sv.x);
    acc.z += blo(sv.y); acc.w += bhi(sv.y);
  }
  float di = dinv[node];
  float4 b4 = *reinterpret_cast<const float4*>(b + q * 4);
  float4 wd4 = *reinterpret_cast<const float4*>(Wd + q * 4);
  float4 wp4 = *reinterpret_cast<const float4*>(Wp + q * 4);
  float vx = fmaxf(fmaf(acc.x, di, b4.x), 0.f);
  float vy = fmaxf(fmaf(acc.y, di, b4.y), 0.f);
  float vz = fmaxf(fmaf(acc.z, di, b4.z), 0.f);
  float vw = fmaxf(fmaf(acc.w, di, b4.w), 0.f);
  float dsum = vx * wd4.x + vy * wd4.y + vz * wd4.z + vw * wd4.w;
  float psum = vx * wp4.x + vy * wp4.y + vz * wp4.z + vw * wp4.w;
#pragma unroll
  for (int off = 1; off < 16; off <<= 1) {
    dsum += __shfl_xor(dsum, off);
    psum += __shfl_xor(psum, off);
  }
  if (lane == 0) {
    out[node] = dsum + bd[0];
    out[n + node] = psum + bp[0];
  }
}

extern "C" void kernel_launch(void* const* d_in, const int* in_sizes, int n_in,
                              void* d_out, int out_size, void* d_ws, size_t ws_size,
                              hipStream_t stream) {
  const float* x  = (const float*)d_in[0];
  const int*   ei = (const int*)d_in[1];
  const float* W1 = (const float*)d_in[2];
  const float* b1 = (const float*)d_in[3];
  const float* W2 = (const float*)d_in[4];
  const float* b2 = (const float*)d_in[5];
  const float* Wd = (const float*)d_in[6];
  const float* bd = (const float*)d_in[7];
  const float* Wp = (const float*)d_in[8];
  const float* bp = (const float*)d_in[9];
  float* out = (float*)d_out;

  const int N = in_sizes[0] / 64;
  const int E = in_sizes[1] / 2;
  const int* src = ei;
  const int* dst = ei + E;
  const int nc = (N + 255) >> 8;  // 391 coarse buckets (<= MAXC)

  char* ws = (char*)d_ws;
  size_t off = 0;
  auto alloc = [&](size_t bytes) -> void* {
    size_t a = (off + 255) & ~(size_t)255;
    off = a + bytes;
    return (void*)(ws + a);
  };

  int*   gcur = (int*)alloc((size_t)MAXC * GPAD * 4);
  int*   rs   = (int*)alloc((size_t)N * 4);
  int*   c    = (int*)alloc((size_t)N * 4);
  float* dinv = (float*)alloc((size_t)N * 4);
  int*   P    = (int*)alloc((size_t)nc * CAP * 4);
  int*   col  = (int*)alloc((size_t)nc * CAP * 4);
  unsigned int* xh  = (unsigned int*)alloc((size_t)N * 64 * 2);
  unsigned int* g2h = (unsigned int*)alloc((size_t)N * 64 * 2);
  float* agg  = (float*)alloc((size_t)N * 64 * 4);
  float* h1   = (float*)alloc((size_t)N * 128 * 4);
  (void)ws_size; (void)n_in; (void)out_size;

  k_binit<<<(nc + 255) / 256, 256, 0, stream>>>(gcur, nc);

  int nb1 = 512;
  int seg = (E + nb1 - 1) / nb1;
  while (seg > SEG) { nb1 *= 2; seg = (E + nb1 - 1) / nb1; }
  k_pass1<<<nb1, 256, 0, stream>>>(src, dst, gcur, P, E, nc, seg);
  k_pass2<<<nc, 256, 0, stream>>>(P, gcur, rs, c, dinv, col, N);

  k_cast<<<(N * 16 + 255) / 256, 256, 0, stream>>>(x, dinv, xh, N * 16);
  k_pull1<<<(N + 3) / 4, 256, 0, stream>>>(xh, rs, c, col, dinv, agg, N);
  k_gemm1<<<512, 256, 0, stream>>>(agg, W1, b1, h1, N);
  k_gemm2<<<512, 256, 0, stream>>>(h1, W2, dinv, g2h, N);
  k_pull2<<<(N + 3) / 4, 256, 0, stream>>>(g2h, rs, c, col, dinv, b2, Wd, Wp, bd, bp, out, N);
}